// Round 15
// baseline (2857.798 us; speedup 1.0000x reference)
//
#include <hip/hip_runtime.h>

typedef unsigned short ushort_t;
typedef __attribute__((ext_vector_type(8))) short v8s;
typedef __attribute__((ext_vector_type(4))) float v4f;
typedef __attribute__((ext_vector_type(4))) unsigned int v4u;
typedef __attribute__((ext_vector_type(4))) unsigned short v4h;

#define DEV __device__ __forceinline__

#define BB 128
#define TT 256
#define DD 256
#define UU 256
#define NG 1024
#define TB 32768  // T*B
#define RW 8      // exchange ring depth (power of 2)

#define L2E  1.4426950408889634f
#define L2E2 2.8853901617779268f

DEV ushort_t f2bf(float f){
  unsigned u = __builtin_bit_cast(unsigned, f);
  u = u + 0x7FFFu + ((u>>16)&1u);
  return (ushort_t)(u>>16);
}
DEV float bf2f(ushort_t h){
  unsigned u = ((unsigned)h)<<16;
  return __builtin_bit_cast(float, u);
}
// ---- L3-coherent exchange ops (proven protocol class: sc0 sc1 everywhere) ----
DEV void st_tag(unsigned* p, unsigned v){
  asm volatile("global_store_dword %0, %1, off sc0 sc1" :: "v"(p), "v"(v) : "memory");
}
DEV v4u ld4_tag(const unsigned* p){
  v4u r;
  asm volatile("global_load_dwordx4 %0, %1, off sc0 sc1" : "=v"(r) : "v"(p) : "memory");
  return r;
}

// ---- prep: x (B,T,D) fp32 -> xb (T,B,D) bf16 ----
__global__ void prep_x(const float* __restrict__ x, ushort_t* __restrict__ xb){
  int tid = blockIdx.x*256 + threadIdx.x;
  int idx = tid*4;
  if (idx >= BB*TT*DD) return;
  int d0 = idx & 255, t = (idx>>8)&255, b = idx>>16;
  const float* s = x + ((size_t)(b*256+t))*256 + d0;
  ushort_t* o = xb + ((size_t)(t*128+b))*256 + d0;
  v4f v = *(const v4f*)s;
  o[0]=f2bf(v[0]); o[1]=f2bf(v[1]); o[2]=f2bf(v[2]); o[3]=f2bf(v[3]);
}

// ---- prep: W (L,K=256,N=1024) fp32 -> wt [d][L][n][k] bf16, pre-scaled by log2e ----
__global__ void prep_w(const float* __restrict__ wf, const float* __restrict__ wb,
                       ushort_t* __restrict__ wt){
  int tid = blockIdx.x*256 + threadIdx.x;           // 1,048,576 total
  int n = tid & 1023, k = (tid>>10)&255, L = (tid>>18)&1, d = (tid>>19)&1;
  const float* src = (d ? wb : wf) + (size_t)L*262144 + (size_t)k*1024 + n;
  float sc = ((n>>8)==2) ? L2E2 : L2E;
  wt[(size_t)((d*2+L)*1024 + n)*256 + k] = f2bf(*src * sc);
}

// ---- prep: R (L,256,1024) fp32 -> rp packed in MFMA B-fragment order, pre-scaled ----
__global__ void prep_r(const float* __restrict__ rf, const float* __restrict__ rb,
                       ushort_t* __restrict__ rp){
  int tid = blockIdx.x*256 + threadIdx.x;           // 1,048,576 total
  int gcol = tid & 1023, k = (tid>>10)&255, L = (tid>>18)&1, d = (tid>>19)&1;
  const float* src = (d ? rb : rf) + (size_t)L*262144 + (size_t)k*1024 + gcol;
  float sc = ((gcol>>8)==2) ? L2E2 : L2E;
  int g = gcol>>8, rem = gcol&255, slot = rem>>4, lo = rem&15;
  int ks = k>>5, hi = (k>>3)&3, j = k&7;
  int l = hi*16+lo, frag = ks*4+g;
  rp[(size_t)((d*2+L)*16 + slot)*16384 + (size_t)frag*512 + l*8 + j] = f2bf(*src * sc);
}

// ---- projection GEMM: xz[d][t*128+b][gc] = A @ W^T + bias*sc (all pre-scaled) ----
__global__ __launch_bounds__(256) void proj_gemm(
    const ushort_t* __restrict__ A_fw, const ushort_t* __restrict__ A_bw,
    const ushort_t* __restrict__ wt, int layer,
    const float* __restrict__ bias_fw, const float* __restrict__ bias_bw,
    ushort_t* __restrict__ xz)
{
  int d = blockIdx.z;
  const ushort_t* A = d ? A_bw : A_fw;
  const ushort_t* W = wt + (size_t)(d*2+layer)*262144;
  const float* bias = (d ? bias_bw : bias_fw) + layer*1024;
  ushort_t* out = xz + (size_t)d*TB*NG;
  int m0 = blockIdx.x*128, n0 = blockIdx.y*128;
  __shared__ ushort_t As[128*32];
  __shared__ ushort_t Bs[128*32];
  int tid = threadIdx.x;
  int w = tid>>6, l = tid&63, lo = l&15, hi = l>>4;
  int wm = w>>1, wn = w&1;
  v4f acc[4][4];
  #pragma unroll
  for (int i=0;i<4;++i)
    #pragma unroll
    for (int j=0;j<4;++j) acc[i][j] = (v4f){0.f,0.f,0.f,0.f};
  for (int kt=0; kt<8; ++kt){
    __syncthreads();
    #pragma unroll
    for (int p=0;p<2;++p){
      int c = tid + p*256;
      int row = c>>2, c4 = c&3;
      *(v4u*)(As + (size_t)c*8) = *(const v4u*)(A + (size_t)(m0+row)*256 + kt*32 + c4*8);
      *(v4u*)(Bs + (size_t)c*8) = *(const v4u*)(W + (size_t)(n0+row)*256 + kt*32 + c4*8);
    }
    __syncthreads();
    v8s af[4], bfv[4];
    #pragma unroll
    for (int mt=0;mt<4;++mt) af[mt] = *(const v8s*)(As + (size_t)(wm*64+mt*16+lo)*32 + hi*8);
    #pragma unroll
    for (int nt=0;nt<4;++nt) bfv[nt] = *(const v8s*)(Bs + (size_t)(wn*64+nt*16+lo)*32 + hi*8);
    #pragma unroll
    for (int mt=0;mt<4;++mt)
      #pragma unroll
      for (int nt=0;nt<4;++nt)
        acc[mt][nt] = __builtin_amdgcn_mfma_f32_16x16x32_bf16(af[mt], bfv[nt], acc[mt][nt], 0,0,0);
  }
  #pragma unroll
  for (int nt=0;nt<4;++nt){
    int col = n0 + wn*64 + nt*16 + lo;
    float bv = bias[col] * (((col>>8)==2) ? L2E2 : L2E);
    #pragma unroll
    for (int mt=0;mt<4;++mt){
      int row0 = m0 + wm*64 + mt*16 + hi*4;
      #pragma unroll
      for (int r=0;r<4;++r)
        out[(size_t)(row0+r)*NG + col] = f2bf(acc[mt][nt][r] + bv);
    }
  }
}

// ---- persistent LSTM recurrence, tagged-RING exchange ----
// 64 blocks x 256 thr (1 wave/SIMD). g = bid&15 (d=g>>3, bg=g&7), cw = bid>>4.
// Exchange: W=8-deep ring of u32 words (bf16<<16 | tag), tag = layer*256+s+1,
// sc0 sc1 stores/loads (L3-coherent). Consumer polls the exact 64 words of its
// A-fragment until every tag reads layer*256+s. The store IS the publication:
// no producer drain, no flag hop. Per-word tag check makes torn 16B reads benign.
// Full h series additionally written as plain bf16 (cross-dispatch consumers).
// Ring wrap safe: in-group producer/consumer skew <= 1 step << RW. Spin bounded.
__global__ __launch_bounds__(256,1) void rec_ring(
    const ushort_t* __restrict__ xz, const ushort_t* __restrict__ rp,
    ushort_t* __restrict__ hbase, unsigned* __restrict__ ring, int layer)
{
  int bid = blockIdx.x;
  int g = bid & 15, cw = bid >> 4;
  int d = g >> 3, bg = g & 7;
  int rev = d;
  int tid = threadIdx.x, w = tid>>6, l = tid&63, lo = l&15, hi = l>>4;
  int b0 = bg*16;
  int U0 = cw*64 + w*16;
  int slot = cw*4 + w;
  const ushort_t* xzd = xz + (size_t)d*TB*NG;
  ushort_t* h = hbase + (size_t)d*TB*UU;
  unsigned* rg = ring + (size_t)d*RW*128*UU;
  unsigned base = (unsigned)layer*256u;

  v8s bfr[8][4];
  {
    const ushort_t* rpp = rp + (size_t)((d*2+layer)*16 + slot)*16384 + l*8;
    #pragma unroll
    for (int f=0;f<32;++f)
      ((v8s*)bfr)[f] = *(const v8s*)(rpp + (size_t)f*512);
  }
  float c[4] = {0.f,0.f,0.f,0.f};

  for (int s=0;s<256;++s){
    int t = rev ? 255-s : s;
    // xz prefetch (read-only stream from prior dispatch; plain cached loads)
    float xzv[4][4];
    #pragma unroll
    for (int gg=0;gg<4;++gg)
      #pragma unroll
      for (int r=0;r<4;++r)
        xzv[gg][r] = bf2f(xzd[(size_t)(t*128 + b0 + hi*4 + r)*NG + gg*256 + U0 + lo]);
    v4f acc[4];
    #pragma unroll
    for (int gg=0;gg<4;++gg) acc[gg] = (v4f){0.f,0.f,0.f,0.f};
    if (s>0){
      int tp = rev ? t+1 : t-1;
      const unsigned* hrow = rg + (size_t)((tp&(RW-1))*128 + b0 + lo)*UU;
      unsigned want = base + (unsigned)s;
      v4u q[16];
      int spin = 0; bool ok;
      do {
        #pragma unroll
        for (int ks=0;ks<8;++ks){
          q[2*ks]   = ld4_tag(hrow + ks*32 + hi*8);
          q[2*ks+1] = ld4_tag(hrow + ks*32 + hi*8 + 4);
        }
        asm volatile("s_waitcnt vmcnt(0)" ::: "memory");
        __builtin_amdgcn_sched_barrier(0);   // rule-18: nothing hoists past the wait
        unsigned badv = 0u;
        #pragma unroll
        for (int i=0;i<16;++i)
          #pragma unroll
          for (int j=0;j<4;++j)
            badv |= (q[i][j] ^ want);
        ok = __all((badv & 0xFFFFu) == 0u);
      } while (!ok && ++spin < 5000);   // failsafe: wrong answer beats hang
      v8s a[8];
      #pragma unroll
      for (int ks=0;ks<8;++ks){
        v4u q0 = q[2*ks], q1 = q[2*ks+1], tm;
        tm[0] = (q0[0]>>16) | (q0[1] & 0xFFFF0000u);
        tm[1] = (q0[2]>>16) | (q0[3] & 0xFFFF0000u);
        tm[2] = (q1[0]>>16) | (q1[1] & 0xFFFF0000u);
        tm[3] = (q1[2]>>16) | (q1[3] & 0xFFFF0000u);
        a[ks] = __builtin_bit_cast(v8s, tm);
      }
      #pragma unroll
      for (int ks=0;ks<8;++ks)
        #pragma unroll
        for (int gg=0;gg<4;++gg)
          acc[gg] = __builtin_amdgcn_mfma_f32_16x16x32_bf16(a[ks], bfr[ks][gg], acc[gg], 0,0,0);
    }
    unsigned tagv = base + (unsigned)s + 1u;
    #pragma unroll
    for (int r=0;r<4;++r){
      float zi = acc[0][r] + xzv[0][r];   // pre-scaled by log2e
      float zf = acc[1][r] + xzv[1][r];
      float zg = acc[2][r] + xzv[2][r];   // pre-scaled by 2*log2e
      float zo = acc[3][r] + xzv[3][r];
      float ig = __builtin_amdgcn_rcpf(1.f + __builtin_amdgcn_exp2f(-zi));
      float fg = __builtin_amdgcn_rcpf(1.f + __builtin_amdgcn_exp2f(-zf));
      float og = __builtin_amdgcn_rcpf(1.f + __builtin_amdgcn_exp2f(-zo));
      float gt = 1.f - 2.f*__builtin_amdgcn_rcpf(1.f + __builtin_amdgcn_exp2f(zg));
      float cc = fg*c[r] + ig*gt;
      c[r] = cc;
      float th = 1.f - 2.f*__builtin_amdgcn_rcpf(1.f + __builtin_amdgcn_exp2f(L2E2*cc));
      ushort_t hv = f2bf(og*th);
      size_t off = (size_t)(t*128 + b0 + hi*4 + r)*UU + U0 + lo;
      // critical-path publication: tagged ring word
      st_tag(rg + (size_t)((t&(RW-1))*128 + b0 + hi*4 + r)*UU + U0 + lo,
             ((unsigned)hv << 16) | tagv);
      // fire-and-forget full series (consumed by proj L1 / combine after dispatch)
      h[off] = hv;
    }
    // no drain, no flag: the tagged ring stores are the publication
  }
}

// ---- final combine: out(B,T,U) fp32 = 0.5*(h1f + h0f + h1b + h0b) ----
__global__ void combine(const ushort_t* __restrict__ h, float* __restrict__ out){
  int tid = blockIdx.x*256 + threadIdx.x;
  int idx = tid*4;
  if (idx >= BB*TT*UU) return;
  int u = idx&255, t = (idx>>8)&255, b = idx>>16;
  size_t o = (size_t)(t*128+b)*256 + u;
  const size_t S = (size_t)TB*UU;
  v4h a0 = *(const v4h*)(h + 0*S + o);   // L0 fw
  v4h a1 = *(const v4h*)(h + 1*S + o);   // L0 bw
  v4h a2 = *(const v4h*)(h + 2*S + o);   // L1 fw
  v4h a3 = *(const v4h*)(h + 3*S + o);   // L1 bw
  v4f res;
  #pragma unroll
  for (int k=0;k<4;++k)
    res[k] = 0.5f*(bf2f(a0[k]) + bf2f(a1[k]) + bf2f(a2[k]) + bf2f(a3[k]));
  *(v4f*)(out + ((size_t)(b*256+t))*256 + u) = res;
}

extern "C" void kernel_launch(void* const* d_in, const int* in_sizes, int n_in,
                              void* d_out, int out_size, void* d_ws, size_t ws_size,
                              hipStream_t stream)
{
  const float* x  = (const float*)d_in[0];
  const float* wf = (const float*)d_in[1];
  const float* rf = (const float*)d_in[2];
  const float* bf = (const float*)d_in[3];
  const float* wb = (const float*)d_in[4];
  const float* rb = (const float*)d_in[5];
  const float* bb = (const float*)d_in[6];
  char* ws = (char*)d_ws;

  // Layout (total 222,298,112 B — within the R10-proven budget):
  //   [0, 16.7MB)  xb  (dead after proj L0)  —  ring (4MB region) ALIASES its head,
  //                 zeroed between proj L0 and rec L0 each launch (stream-ordered).
  const size_t XB_OFF = 0;
  const size_t WT_OFF = XB_OFF + (size_t)TB*DD*2;            // 16,777,216
  const size_t RP_OFF = WT_OFF + (size_t)2*2*1024*256*2;     // +2,097,152
  const size_t XZ_OFF = RP_OFF + (size_t)2*2*256*1024*2;     // +2,097,152
  const size_t H_OFF  = XZ_OFF + (size_t)2*TB*NG*2;          // +134,217,728
  const size_t RING_BYTES = (size_t)2*RW*128*UU*4;           // 2,097,152

  ushort_t* xb = (ushort_t*)(ws + XB_OFF);
  ushort_t* wt = (ushort_t*)(ws + WT_OFF);
  ushort_t* rp = (ushort_t*)(ws + RP_OFF);
  ushort_t* xz = (ushort_t*)(ws + XZ_OFF);
  ushort_t* h  = (ushort_t*)(ws + H_OFF);
  unsigned* ring = (unsigned*)(ws + XB_OFF);   // aliases xb (dead after proj L0)
  const size_t S = (size_t)TB*UU;

  prep_x<<<8192,256,0,stream>>>(x, xb);
  prep_w<<<4096,256,0,stream>>>(wf, wb, wt);
  prep_r<<<4096,256,0,stream>>>(rf, rb, rp);
  // layer 0
  proj_gemm<<<dim3(256,8,2),256,0,stream>>>(xb, xb, wt, 0, bf, bb, xz);
  hipMemsetAsync(ring, 0, RING_BYTES, stream);   // xb dead from here; clear ring tags
  rec_ring<<<64,256,0,stream>>>(xz, rp, h, ring, 0);
  // layer 1 (input = plain L0 h series; residual handled in combine)
  proj_gemm<<<dim3(256,8,2),256,0,stream>>>(h, h + S, wt, 1, bf, bb, xz);
  rec_ring<<<64,256,0,stream>>>(xz, rp, h + 2*S, ring, 1);
  // merge: 0.5*((h1f+h0f)+(h1b+h0b))
  combine<<<8192,256,0,stream>>>(h, (float*)d_out);
}

// Round 16
// 1278.178 us; speedup vs baseline: 2.2358x; 2.2358x over previous
//
#include <hip/hip_runtime.h>

typedef unsigned short ushort_t;
typedef __attribute__((ext_vector_type(8))) short v8s;
typedef __attribute__((ext_vector_type(4))) float v4f;
typedef __attribute__((ext_vector_type(4))) unsigned int v4u;
typedef __attribute__((ext_vector_type(4))) unsigned short v4h;

#define DEV __device__ __forceinline__

#define BB 128
#define TT 256
#define DD 256
#define UU 256
#define NG 1024
#define TB 32768  // T*B

#define L2E  1.4426950408889634f
#define L2E2 2.8853901617779268f

DEV ushort_t f2bf(float f){
  unsigned u = __builtin_bit_cast(unsigned, f);
  u = u + 0x7FFFu + ((u>>16)&1u);
  return (ushort_t)(u>>16);
}
DEV float bf2f(ushort_t h){
  unsigned u = ((unsigned)h)<<16;
  return __builtin_bit_cast(float, u);
}
// write-through store (L3-visible; proven R10 protocol)
DEV void store_short_wt(ushort_t* p, ushort_t v){
  asm volatile("global_store_short %0, %1, off sc0 sc1" :: "v"(p), "v"((unsigned)v) : "memory");
}

// ---- prep: x (B,T,D) fp32 -> xb (T,B,D) bf16 ----
__global__ void prep_x(const float* __restrict__ x, ushort_t* __restrict__ xb){
  int tid = blockIdx.x*256 + threadIdx.x;
  int idx = tid*4;
  if (idx >= BB*TT*DD) return;
  int d0 = idx & 255, t = (idx>>8)&255, b = idx>>16;
  const float* s = x + ((size_t)(b*256+t))*256 + d0;
  ushort_t* o = xb + ((size_t)(t*128+b))*256 + d0;
  v4f v = *(const v4f*)s;
  o[0]=f2bf(v[0]); o[1]=f2bf(v[1]); o[2]=f2bf(v[2]); o[3]=f2bf(v[3]);
}

// ---- prep: W layer 0 (K=256,N=1024) fp32 -> wt [d][n][k] bf16, pre-scaled by log2e ----
__global__ void prep_w(const float* __restrict__ wf, const float* __restrict__ wb,
                       ushort_t* __restrict__ wt){
  int tid = blockIdx.x*256 + threadIdx.x;           // 524,288 total
  int n = tid & 1023, k = (tid>>10)&255, d = (tid>>18)&1;
  const float* src = (d ? wb : wf) + (size_t)k*1024 + n;   // layer 0
  float sc = ((n>>8)==2) ? L2E2 : L2E;
  wt[(size_t)(d*1024 + n)*256 + k] = f2bf(*src * sc);
}

// ---- prep: R (both layers) fp32 -> rp packed in MFMA B-fragment order, pre-scaled ----
__global__ void prep_r(const float* __restrict__ rf, const float* __restrict__ rb,
                       ushort_t* __restrict__ rp){
  int tid = blockIdx.x*256 + threadIdx.x;           // 1,048,576 total
  int gcol = tid & 1023, k = (tid>>10)&255, L = (tid>>18)&1, d = (tid>>19)&1;
  const float* src = (d ? rb : rf) + (size_t)L*262144 + (size_t)k*1024 + gcol;
  float sc = ((gcol>>8)==2) ? L2E2 : L2E;
  int g = gcol>>8, rem = gcol&255, slot = rem>>4, lo = rem&15;
  int ks = k>>5, hi = (k>>3)&3, j = k&7;
  int l = hi*16+lo, frag = ks*4+g;
  rp[(size_t)((d*2+L)*16 + slot)*16384 + (size_t)frag*512 + l*8 + j] = f2bf(*src * sc);
}

// ---- prep: W layer 1 fp32 -> wp packed in MFMA B-fragment order, pre-scaled ----
__global__ void prep_wf(const float* __restrict__ wf, const float* __restrict__ wb,
                        ushort_t* __restrict__ wp){
  int tid = blockIdx.x*256 + threadIdx.x;           // 524,288 total
  int gcol = tid & 1023, k = (tid>>10)&255, d = (tid>>18)&1;
  const float* src = (d ? wb : wf) + 262144 + (size_t)k*1024 + gcol;  // layer 1
  float sc = ((gcol>>8)==2) ? L2E2 : L2E;
  int g = gcol>>8, rem = gcol&255, slot = rem>>4, lo = rem&15;
  int ks = k>>5, hi = (k>>3)&3, j = k&7;
  int l = hi*16+lo, frag = ks*4+g;
  wp[(size_t)(d*16 + slot)*16384 + (size_t)frag*512 + l*8 + j] = f2bf(*src * sc);
}

// ---- projection GEMM (layer 0 only): xz[d][t*128+b][gc] = xb @ W0^T + b0*sc ----
__global__ __launch_bounds__(256) void proj_gemm(
    const ushort_t* __restrict__ A,
    const ushort_t* __restrict__ wt,
    const float* __restrict__ bias_fw, const float* __restrict__ bias_bw,
    ushort_t* __restrict__ xz)
{
  int d = blockIdx.z;
  const ushort_t* W = wt + (size_t)d*262144;
  const float* bias = (d ? bias_bw : bias_fw);      // layer 0 row
  ushort_t* out = xz + (size_t)d*TB*NG;
  int m0 = blockIdx.x*128, n0 = blockIdx.y*128;
  __shared__ ushort_t As[128*32];
  __shared__ ushort_t Bs[128*32];
  int tid = threadIdx.x;
  int w = tid>>6, l = tid&63, lo = l&15, hi = l>>4;
  int wm = w>>1, wn = w&1;
  v4f acc[4][4];
  #pragma unroll
  for (int i=0;i<4;++i)
    #pragma unroll
    for (int j=0;j<4;++j) acc[i][j] = (v4f){0.f,0.f,0.f,0.f};
  for (int kt=0; kt<8; ++kt){
    __syncthreads();
    #pragma unroll
    for (int p=0;p<2;++p){
      int c = tid + p*256;
      int row = c>>2, c4 = c&3;
      *(v4u*)(As + (size_t)c*8) = *(const v4u*)(A + (size_t)(m0+row)*256 + kt*32 + c4*8);
      *(v4u*)(Bs + (size_t)c*8) = *(const v4u*)(W + (size_t)(n0+row)*256 + kt*32 + c4*8);
    }
    __syncthreads();
    v8s af[4], bfv[4];
    #pragma unroll
    for (int mt=0;mt<4;++mt) af[mt] = *(const v8s*)(As + (size_t)(wm*64+mt*16+lo)*32 + hi*8);
    #pragma unroll
    for (int nt=0;nt<4;++nt) bfv[nt] = *(const v8s*)(Bs + (size_t)(wn*64+nt*16+lo)*32 + hi*8);
    #pragma unroll
    for (int mt=0;mt<4;++mt)
      #pragma unroll
      for (int nt=0;nt<4;++nt)
        acc[mt][nt] = __builtin_amdgcn_mfma_f32_16x16x32_bf16(af[mt], bfv[nt], acc[mt][nt], 0,0,0);
  }
  #pragma unroll
  for (int nt=0;nt<4;++nt){
    int col = n0 + wn*64 + nt*16 + lo;
    float bv = bias[col] * (((col>>8)==2) ? L2E2 : L2E);
    #pragma unroll
    for (int mt=0;mt<4;++mt){
      int row0 = m0 + wm*64 + mt*16 + hi*4;
      #pragma unroll
      for (int r=0;r<4;++r)
        out[(size_t)(row0+r)*NG + col] = f2bf(acc[mt][nt][r] + bv);
    }
  }
}

// ---- FUSED two-layer persistent recurrence ----
// 128 blocks x 256 thr (1 wave/SIMD). Decode: cw = bid>>5; rem = bid&31;
// L = rem>>4, d = (rem>>3)&1, bg = rem&7. Flags: group (L,d,bg) has 256x16 slots.
// L0 role: exactly the R10-proven loop (xz stream + R0 frags, publish flg0).
// L1 role: holds W1 AND R1 fragment slices in registers; per step s waits for
//   flg0[s] (h0[t] ready) and flg1[s-1] (own chain), computes
//   z = h0[t]@W1 + h1[t-1]@R1 + b1, publishes flg1[s]. No xz pass for layer 1.
// L1 lags L0 by ~1 step -> rec critical path ~257 steps instead of 512.
// All consumer h loads are first-touch-per-line (R10-proven safe with plain loads).
// All spins BOUNDED: wrong answer beats hang.
__global__ __launch_bounds__(256,1) void rec_fused(
    const ushort_t* __restrict__ xz, const ushort_t* __restrict__ rp,
    const ushort_t* __restrict__ wp,
    const float* __restrict__ bias_fw, const float* __restrict__ bias_bw,
    ushort_t* __restrict__ hbase, unsigned* __restrict__ flags)
{
  int bid = blockIdx.x;
  int cw = bid >> 5, rem = bid & 31;
  int L = rem >> 4, d = (rem >> 3) & 1, bg = rem & 7;
  int rev = d;
  int tid = threadIdx.x, w = tid>>6, l = tid&63, lo = l&15, hi = l>>4;
  int b0 = bg*16;
  int U0 = cw*64 + w*16;
  int slot = cw*4 + w;
  const size_t S = (size_t)TB*UU;
  unsigned* flg0 = flags + (size_t)((0*2+d)*8+bg)*4096;
  unsigned* flg1 = flags + (size_t)((1*2+d)*8+bg)*4096;

  if (L == 0){
    // ---------------- layer-0 role: R10-proven loop ----------------
    const ushort_t* xzd = xz + (size_t)d*TB*NG;
    ushort_t* h = hbase + (size_t)d*S;
    v8s bfr[8][4];
    {
      const ushort_t* rpp = rp + (size_t)((d*2+0)*16 + slot)*16384 + l*8;
      #pragma unroll
      for (int f=0;f<32;++f)
        ((v8s*)bfr)[f] = *(const v8s*)(rpp + (size_t)f*512);
    }
    float c[4] = {0.f,0.f,0.f,0.f};
    for (int s=0;s<256;++s){
      int t = rev ? 255-s : s;
      float xzv[4][4];
      #pragma unroll
      for (int gg=0;gg<4;++gg)
        #pragma unroll
        for (int r=0;r<4;++r)
          xzv[gg][r] = bf2f(xzd[(size_t)(t*128 + b0 + hi*4 + r)*NG + gg*256 + U0 + lo]);
      v4f acc[4];
      #pragma unroll
      for (int gg=0;gg<4;++gg) acc[gg] = (v4f){0.f,0.f,0.f,0.f};
      if (s>0){
        unsigned v; int spin = 0;
        do {
          v = __hip_atomic_load(&flg0[(s-1)*16 + (l&15)], __ATOMIC_RELAXED, __HIP_MEMORY_SCOPE_AGENT);
          if (++spin > 8000) break;   // failsafe
        } while (!__all(v != 0u));
        asm volatile("" ::: "memory");
        int tp = rev ? t+1 : t-1;
        v8s a[8];
        #pragma unroll
        for (int ks=0;ks<8;++ks)
          a[ks] = *(const v8s*)(h + (size_t)(tp*128 + b0 + lo)*UU + ks*32 + hi*8);
        #pragma unroll
        for (int ks=0;ks<8;++ks)
          #pragma unroll
          for (int gg=0;gg<4;++gg)
            acc[gg] = __builtin_amdgcn_mfma_f32_16x16x32_bf16(a[ks], bfr[ks][gg], acc[gg], 0,0,0);
      }
      #pragma unroll
      for (int r=0;r<4;++r){
        float zi = acc[0][r] + xzv[0][r];
        float zf = acc[1][r] + xzv[1][r];
        float zg = acc[2][r] + xzv[2][r];
        float zo = acc[3][r] + xzv[3][r];
        float ig = __builtin_amdgcn_rcpf(1.f + __builtin_amdgcn_exp2f(-zi));
        float fg = __builtin_amdgcn_rcpf(1.f + __builtin_amdgcn_exp2f(-zf));
        float og = __builtin_amdgcn_rcpf(1.f + __builtin_amdgcn_exp2f(-zo));
        float gt = 1.f - 2.f*__builtin_amdgcn_rcpf(1.f + __builtin_amdgcn_exp2f(zg));
        float cc = fg*c[r] + ig*gt;
        c[r] = cc;
        float th = 1.f - 2.f*__builtin_amdgcn_rcpf(1.f + __builtin_amdgcn_exp2f(L2E2*cc));
        store_short_wt(h + (size_t)(t*128 + b0 + hi*4 + r)*UU + U0 + lo, f2bf(og*th));
      }
      asm volatile("s_waitcnt vmcnt(0)" ::: "memory");
      if (l == 0)
        __hip_atomic_store(&flg0[s*16 + slot], 1u, __ATOMIC_RELAXED, __HIP_MEMORY_SCOPE_AGENT);
    }
  } else {
    // ---------------- layer-1 role: W1 + R1 in registers ----------------
    const ushort_t* h0 = hbase + (size_t)d*S;          // read (L0 output)
    ushort_t* h1 = hbase + (size_t)(2+d)*S;            // write
    v8s bfr[8][4], bfw[8][4];
    {
      const ushort_t* rpp = rp + (size_t)((d*2+1)*16 + slot)*16384 + l*8;
      const ushort_t* wpp = wp + (size_t)(d*16 + slot)*16384 + l*8;
      #pragma unroll
      for (int f=0;f<32;++f){
        ((v8s*)bfr)[f] = *(const v8s*)(rpp + (size_t)f*512);
        ((v8s*)bfw)[f] = *(const v8s*)(wpp + (size_t)f*512);
      }
    }
    const float* bias = (d ? bias_bw : bias_fw) + 1024;   // layer 1 row
    float bv[4];
    #pragma unroll
    for (int gg=0;gg<4;++gg)
      bv[gg] = bias[gg*256 + U0 + lo] * ((gg==2) ? L2E2 : L2E);
    float c[4] = {0.f,0.f,0.f,0.f};
    for (int s=0;s<256;++s){
      int t = rev ? 255-s : s;
      // wait for h0[t] (flg0[s]) and own h1[t-1] (flg1[s-1])
      {
        unsigned va, vb; int spin = 0;
        const unsigned* fpa = &flg0[s*16 + (l&15)];
        const unsigned* fpb = &flg1[(s>0 ? s-1 : 0)*16 + (l&15)];
        do {
          va = __hip_atomic_load(fpa, __ATOMIC_RELAXED, __HIP_MEMORY_SCOPE_AGENT);
          vb = (s>0) ? __hip_atomic_load(fpb, __ATOMIC_RELAXED, __HIP_MEMORY_SCOPE_AGENT) : 1u;
          if (++spin > 8000) break;   // failsafe
        } while (!__all((va != 0u) && (vb != 0u)));
        asm volatile("" ::: "memory");
      }
      v4f acc[4];
      #pragma unroll
      for (int gg=0;gg<4;++gg) acc[gg] = (v4f){0.f,0.f,0.f,0.f};
      // a0 = h0[t] fragments (first-touch lines)
      {
        v8s a0[8];
        #pragma unroll
        for (int ks=0;ks<8;++ks)
          a0[ks] = *(const v8s*)(h0 + (size_t)(t*128 + b0 + lo)*UU + ks*32 + hi*8);
        #pragma unroll
        for (int ks=0;ks<8;++ks)
          #pragma unroll
          for (int gg=0;gg<4;++gg)
            acc[gg] = __builtin_amdgcn_mfma_f32_16x16x32_bf16(a0[ks], bfw[ks][gg], acc[gg], 0,0,0);
      }
      if (s>0){
        int tp = rev ? t+1 : t-1;
        v8s a1[8];
        #pragma unroll
        for (int ks=0;ks<8;++ks)
          a1[ks] = *(const v8s*)(h1 + (size_t)(tp*128 + b0 + lo)*UU + ks*32 + hi*8);
        #pragma unroll
        for (int ks=0;ks<8;++ks)
          #pragma unroll
          for (int gg=0;gg<4;++gg)
            acc[gg] = __builtin_amdgcn_mfma_f32_16x16x32_bf16(a1[ks], bfr[ks][gg], acc[gg], 0,0,0);
      }
      #pragma unroll
      for (int r=0;r<4;++r){
        float zi = acc[0][r] + bv[0];
        float zf = acc[1][r] + bv[1];
        float zg = acc[2][r] + bv[2];
        float zo = acc[3][r] + bv[3];
        float ig = __builtin_amdgcn_rcpf(1.f + __builtin_amdgcn_exp2f(-zi));
        float fg = __builtin_amdgcn_rcpf(1.f + __builtin_amdgcn_exp2f(-zf));
        float og = __builtin_amdgcn_rcpf(1.f + __builtin_amdgcn_exp2f(-zo));
        float gt = 1.f - 2.f*__builtin_amdgcn_rcpf(1.f + __builtin_amdgcn_exp2f(zg));
        float cc = fg*c[r] + ig*gt;
        c[r] = cc;
        float th = 1.f - 2.f*__builtin_amdgcn_rcpf(1.f + __builtin_amdgcn_exp2f(L2E2*cc));
        store_short_wt(h1 + (size_t)(t*128 + b0 + hi*4 + r)*UU + U0 + lo, f2bf(og*th));
      }
      asm volatile("s_waitcnt vmcnt(0)" ::: "memory");
      if (l == 0)
        __hip_atomic_store(&flg1[s*16 + slot], 1u, __ATOMIC_RELAXED, __HIP_MEMORY_SCOPE_AGENT);
    }
  }
}

// ---- final combine: out(B,T,U) fp32 = 0.5*(h1f + h0f + h1b + h0b) ----
__global__ void combine(const ushort_t* __restrict__ h, float* __restrict__ out){
  int tid = blockIdx.x*256 + threadIdx.x;
  int idx = tid*4;
  if (idx >= BB*TT*UU) return;
  int u = idx&255, t = (idx>>8)&255, b = idx>>16;
  size_t o = (size_t)(t*128+b)*256 + u;
  const size_t S = (size_t)TB*UU;
  v4h a0 = *(const v4h*)(h + 0*S + o);   // L0 fw
  v4h a1 = *(const v4h*)(h + 1*S + o);   // L0 bw
  v4h a2 = *(const v4h*)(h + 2*S + o);   // L1 fw
  v4h a3 = *(const v4h*)(h + 3*S + o);   // L1 bw
  v4f res;
  #pragma unroll
  for (int k=0;k<4;++k)
    res[k] = 0.5f*(bf2f(a0[k]) + bf2f(a1[k]) + bf2f(a2[k]) + bf2f(a3[k]));
  *(v4f*)(out + ((size_t)(b*256+t))*256 + u) = res;
}

extern "C" void kernel_launch(void* const* d_in, const int* in_sizes, int n_in,
                              void* d_out, int out_size, void* d_ws, size_t ws_size,
                              hipStream_t stream)
{
  const float* x  = (const float*)d_in[0];
  const float* wf = (const float*)d_in[1];
  const float* rf = (const float*)d_in[2];
  const float* bf = (const float*)d_in[3];
  const float* wb = (const float*)d_in[4];
  const float* rb = (const float*)d_in[5];
  const float* bb = (const float*)d_in[6];
  char* ws = (char*)d_ws;

  // Layout (max 221.9 MB, within the R10-proven budget):
  //   xb [0, 16.7MB) dead after proj L0 -> wp (2MB) + flags (0.5MB) alias it.
  const size_t XB_OFF = 0;
  const size_t WT_OFF = XB_OFF + (size_t)TB*DD*2;            // 16,777,216
  const size_t RP_OFF = WT_OFF + (size_t)2*1024*256*2;       // +1,048,576
  const size_t XZ_OFF = RP_OFF + (size_t)2*2*256*1024*2;     // +2,097,152
  const size_t H_OFF  = XZ_OFF + (size_t)2*TB*NG*2;          // +134,217,728
  const size_t WP_OFF = XB_OFF;                               // aliases xb
  const size_t FL_OFF = XB_OFF + (size_t)2*256*1024*2;        // aliases xb, after wp
  const size_t FL_BYTES = (size_t)32*4096*4;                  // 524,288

  ushort_t* xb = (ushort_t*)(ws + XB_OFF);
  ushort_t* wt = (ushort_t*)(ws + WT_OFF);
  ushort_t* rp = (ushort_t*)(ws + RP_OFF);
  ushort_t* xz = (ushort_t*)(ws + XZ_OFF);
  ushort_t* h  = (ushort_t*)(ws + H_OFF);
  ushort_t* wp = (ushort_t*)(ws + WP_OFF);
  unsigned* flags = (unsigned*)(ws + FL_OFF);

  prep_x<<<8192,256,0,stream>>>(x, xb);
  prep_w<<<2048,256,0,stream>>>(wf, wb, wt);
  prep_r<<<4096,256,0,stream>>>(rf, rb, rp);
  // layer-0 projection (layer 1 is computed inside the fused recurrence)
  proj_gemm<<<dim3(256,8,2),256,0,stream>>>(xb, wt, bf, bb, xz);
  // xb dead from here: pack W1 fragments + zero flags into its region
  prep_wf<<<2048,256,0,stream>>>(wf, wb, wp);
  hipMemsetAsync(flags, 0, FL_BYTES, stream);
  // fused both-layer recurrence (128 persistent blocks)
  rec_fused<<<128,256,0,stream>>>(xz, rp, wp, bf, bb, h, flags);
  // merge: 0.5*((h1f+h0f)+(h1b+h0b))
  combine<<<8192,256,0,stream>>>(h, (float*)d_out);
}

// Round 18
// 1203.231 us; speedup vs baseline: 2.3751x; 1.0623x over previous
//
#include <hip/hip_runtime.h>

typedef unsigned short ushort_t;
typedef __attribute__((ext_vector_type(8))) short v8s;
typedef __attribute__((ext_vector_type(4))) float v4f;
typedef __attribute__((ext_vector_type(4))) unsigned int v4u;
typedef __attribute__((ext_vector_type(4))) unsigned short v4h;

#define DEV __device__ __forceinline__

#define BB 128
#define TT 256
#define DD 256
#define UU 256
#define NG 1024
#define TB 32768  // T*B

#define L2E  1.4426950408889634f
#define L2E2 2.8853901617779268f

DEV ushort_t f2bf(float f){
  unsigned u = __builtin_bit_cast(unsigned, f);
  u = u + 0x7FFFu + ((u>>16)&1u);
  return (ushort_t)(u>>16);
}
DEV float bf2f(ushort_t h){
  unsigned u = ((unsigned)h)<<16;
  return __builtin_bit_cast(float, u);
}
// write-through store (L3-visible; proven R10 protocol)
DEV void store_short_wt(ushort_t* p, ushort_t v){
  asm volatile("global_store_short %0, %1, off sc0 sc1" :: "v"(p), "v"((unsigned)v) : "memory");
}
// paired flag load: both issued, one wait -> one RTT per poll iteration
DEV void ld2_flags(const unsigned* pa, const unsigned* pb, unsigned& va, unsigned& vb){
  asm volatile("global_load_dword %0, %2, off sc1\n\t"
               "global_load_dword %1, %3, off sc1\n\t"
               "s_waitcnt vmcnt(0)"
               : "=v"(va), "=v"(vb) : "v"(pa), "v"(pb) : "memory");
}

// ---- prep: x (B,T,D) fp32 -> xb (T,B,D) bf16 ----
__global__ void prep_x(const float* __restrict__ x, ushort_t* __restrict__ xb){
  int tid = blockIdx.x*256 + threadIdx.x;
  int idx = tid*4;
  if (idx >= BB*TT*DD) return;
  int d0 = idx & 255, t = (idx>>8)&255, b = idx>>16;
  const float* s = x + ((size_t)(b*256+t))*256 + d0;
  ushort_t* o = xb + ((size_t)(t*128+b))*256 + d0;
  v4f v = *(const v4f*)s;
  o[0]=f2bf(v[0]); o[1]=f2bf(v[1]); o[2]=f2bf(v[2]); o[3]=f2bf(v[3]);
}

// ---- prep: W layer 0 (K=256,N=1024) fp32 -> wt [d][n][k] bf16, pre-scaled by log2e ----
__global__ void prep_w(const float* __restrict__ wf, const float* __restrict__ wb,
                       ushort_t* __restrict__ wt){
  int tid = blockIdx.x*256 + threadIdx.x;           // 524,288 total
  int n = tid & 1023, k = (tid>>10)&255, d = (tid>>18)&1;
  const float* src = (d ? wb : wf) + (size_t)k*1024 + n;   // layer 0
  float sc = ((n>>8)==2) ? L2E2 : L2E;
  wt[(size_t)(d*1024 + n)*256 + k] = f2bf(*src * sc);
}

// ---- prep: R (both layers) fp32 -> rp packed in MFMA B-fragment order, pre-scaled ----
__global__ void prep_r(const float* __restrict__ rf, const float* __restrict__ rb,
                       ushort_t* __restrict__ rp){
  int tid = blockIdx.x*256 + threadIdx.x;           // 1,048,576 total
  int gcol = tid & 1023, k = (tid>>10)&255, L = (tid>>18)&1, d = (tid>>19)&1;
  const float* src = (d ? rb : rf) + (size_t)L*262144 + (size_t)k*1024 + gcol;
  float sc = ((gcol>>8)==2) ? L2E2 : L2E;
  int g = gcol>>8, rem = gcol&255, slot = rem>>4, lo = rem&15;
  int ks = k>>5, hi = (k>>3)&3, j = k&7;
  int l = hi*16+lo, frag = ks*4+g;
  rp[(size_t)((d*2+L)*16 + slot)*16384 + (size_t)frag*512 + l*8 + j] = f2bf(*src * sc);
}

// ---- prep: W layer 1 fp32 -> wp packed in MFMA B-fragment order, pre-scaled ----
__global__ void prep_wf(const float* __restrict__ wf, const float* __restrict__ wb,
                        ushort_t* __restrict__ wp){
  int tid = blockIdx.x*256 + threadIdx.x;           // 524,288 total
  int gcol = tid & 1023, k = (tid>>10)&255, d = (tid>>18)&1;
  const float* src = (d ? wb : wf) + 262144 + (size_t)k*1024 + gcol;  // layer 1
  float sc = ((gcol>>8)==2) ? L2E2 : L2E;
  int g = gcol>>8, rem = gcol&255, slot = rem>>4, lo = rem&15;
  int ks = k>>5, hi = (k>>3)&3, j = k&7;
  int l = hi*16+lo, frag = ks*4+g;
  wp[(size_t)(d*16 + slot)*16384 + (size_t)frag*512 + l*8 + j] = f2bf(*src * sc);
}

// ---- projection GEMM (layer 0 only): xz[d][t*128+b][gc] = xb @ W0^T + b0*sc ----
__global__ __launch_bounds__(256) void proj_gemm(
    const ushort_t* __restrict__ A,
    const ushort_t* __restrict__ wt,
    const float* __restrict__ bias_fw, const float* __restrict__ bias_bw,
    ushort_t* __restrict__ xz)
{
  int d = blockIdx.z;
  const ushort_t* W = wt + (size_t)d*262144;
  const float* bias = (d ? bias_bw : bias_fw);      // layer 0 row
  ushort_t* out = xz + (size_t)d*TB*NG;
  int m0 = blockIdx.x*128, n0 = blockIdx.y*128;
  __shared__ ushort_t As[128*32];
  __shared__ ushort_t Bs[128*32];
  int tid = threadIdx.x;
  int w = tid>>6, l = tid&63, lo = l&15, hi = l>>4;
  int wm = w>>1, wn = w&1;
  v4f acc[4][4];
  #pragma unroll
  for (int i=0;i<4;++i)
    #pragma unroll
    for (int j=0;j<4;++j) acc[i][j] = (v4f){0.f,0.f,0.f,0.f};
  for (int kt=0; kt<8; ++kt){
    __syncthreads();
    #pragma unroll
    for (int p=0;p<2;++p){
      int c = tid + p*256;
      int row = c>>2, c4 = c&3;
      *(v4u*)(As + (size_t)c*8) = *(const v4u*)(A + (size_t)(m0+row)*256 + kt*32 + c4*8);
      *(v4u*)(Bs + (size_t)c*8) = *(const v4u*)(W + (size_t)(n0+row)*256 + kt*32 + c4*8);
    }
    __syncthreads();
    v8s af[4], bfv[4];
    #pragma unroll
    for (int mt=0;mt<4;++mt) af[mt] = *(const v8s*)(As + (size_t)(wm*64+mt*16+lo)*32 + hi*8);
    #pragma unroll
    for (int nt=0;nt<4;++nt) bfv[nt] = *(const v8s*)(Bs + (size_t)(wn*64+nt*16+lo)*32 + hi*8);
    #pragma unroll
    for (int mt=0;mt<4;++mt)
      #pragma unroll
      for (int nt=0;nt<4;++nt)
        acc[mt][nt] = __builtin_amdgcn_mfma_f32_16x16x32_bf16(af[mt], bfv[nt], acc[mt][nt], 0,0,0);
  }
  #pragma unroll
  for (int nt=0;nt<4;++nt){
    int col = n0 + wn*64 + nt*16 + lo;
    float bv = bias[col] * (((col>>8)==2) ? L2E2 : L2E);
    #pragma unroll
    for (int mt=0;mt<4;++mt){
      int row0 = m0 + wm*64 + mt*16 + hi*4;
      #pragma unroll
      for (int r=0;r<4;++r)
        out[(size_t)(row0+r)*NG + col] = f2bf(acc[mt][nt][r] + bv);
    }
  }
}

// ---- FUSED two-layer persistent recurrence, BLOCK-level flags ----
// 128 blocks x 256 thr (1 wave/SIMD). Decode: cw = bid>>5; rem = bid&31;
// L = rem>>4, d = (rem>>3)&1, bg = rem&7. Flags: group (L,d,bg) has 256x4 slots
// (one per block-cw). Publish: per-wave vmcnt(0) drain -> __syncthreads (all 4
// waves drained) -> tid0 stores flg[s*4+cw]. Poll: lanes read flg[s*4+(l&3)],
// __all over the wave covers all 4 publishers. 4 same-sector stores/step instead
// of 16 -> less L3 serialization + lower publisher-skew max.
// L1 role waits {flg0[s], flg1[s-1]} with paired loads (one RTT per iteration).
// All spins BOUNDED: wrong answer beats hang.
__global__ __launch_bounds__(256,1) void rec_fused(
    const ushort_t* __restrict__ xz, const ushort_t* __restrict__ rp,
    const ushort_t* __restrict__ wp,
    const float* __restrict__ bias_fw, const float* __restrict__ bias_bw,
    ushort_t* __restrict__ hbase, unsigned* __restrict__ flags)
{
  int bid = blockIdx.x;
  int cw = bid >> 5, rem = bid & 31;
  int L = rem >> 4, d = (rem >> 3) & 1, bg = rem & 7;
  int rev = d;
  int tid = threadIdx.x, w = tid>>6, l = tid&63, lo = l&15, hi = l>>4;
  int b0 = bg*16;
  int U0 = cw*64 + w*16;
  int slot = cw*4 + w;
  const size_t S = (size_t)TB*UU;
  unsigned* flg0 = flags + (size_t)((0*2+d)*8+bg)*1024;   // 256 steps x 4 block-slots
  unsigned* flg1 = flags + (size_t)((1*2+d)*8+bg)*1024;

  if (L == 0){
    // ---------------- layer-0 role ----------------
    const ushort_t* xzd = xz + (size_t)d*TB*NG;
    ushort_t* h = hbase + (size_t)d*S;
    v8s bfr[8][4];
    {
      const ushort_t* rpp = rp + (size_t)((d*2+0)*16 + slot)*16384 + l*8;
      #pragma unroll
      for (int f=0;f<32;++f)
        ((v8s*)bfr)[f] = *(const v8s*)(rpp + (size_t)f*512);
    }
    float c[4] = {0.f,0.f,0.f,0.f};
    for (int s=0;s<256;++s){
      int t = rev ? 255-s : s;
      float xzv[4][4];
      #pragma unroll
      for (int gg=0;gg<4;++gg)
        #pragma unroll
        for (int r=0;r<4;++r)
          xzv[gg][r] = bf2f(xzd[(size_t)(t*128 + b0 + hi*4 + r)*NG + gg*256 + U0 + lo]);
      v4f acc[4];
      #pragma unroll
      for (int gg=0;gg<4;++gg) acc[gg] = (v4f){0.f,0.f,0.f,0.f};
      if (s>0){
        unsigned v; int spin = 0;
        do {
          v = __hip_atomic_load(&flg0[(s-1)*4 + (l&3)], __ATOMIC_RELAXED, __HIP_MEMORY_SCOPE_AGENT);
          if (++spin > 10000) break;   // failsafe
        } while (!__all(v != 0u));
        asm volatile("" ::: "memory");
        int tp = rev ? t+1 : t-1;
        v8s a[8];
        #pragma unroll
        for (int ks=0;ks<8;++ks)
          a[ks] = *(const v8s*)(h + (size_t)(tp*128 + b0 + lo)*UU + ks*32 + hi*8);
        #pragma unroll
        for (int ks=0;ks<8;++ks)
          #pragma unroll
          for (int gg=0;gg<4;++gg)
            acc[gg] = __builtin_amdgcn_mfma_f32_16x16x32_bf16(a[ks], bfr[ks][gg], acc[gg], 0,0,0);
      }
      #pragma unroll
      for (int r=0;r<4;++r){
        float zi = acc[0][r] + xzv[0][r];
        float zf = acc[1][r] + xzv[1][r];
        float zg = acc[2][r] + xzv[2][r];
        float zo = acc[3][r] + xzv[3][r];
        float ig = __builtin_amdgcn_rcpf(1.f + __builtin_amdgcn_exp2f(-zi));
        float fg = __builtin_amdgcn_rcpf(1.f + __builtin_amdgcn_exp2f(-zf));
        float og = __builtin_amdgcn_rcpf(1.f + __builtin_amdgcn_exp2f(-zo));
        float gt = 1.f - 2.f*__builtin_amdgcn_rcpf(1.f + __builtin_amdgcn_exp2f(zg));
        float cc = fg*c[r] + ig*gt;
        c[r] = cc;
        float th = 1.f - 2.f*__builtin_amdgcn_rcpf(1.f + __builtin_amdgcn_exp2f(L2E2*cc));
        store_short_wt(h + (size_t)(t*128 + b0 + hi*4 + r)*UU + U0 + lo, f2bf(og*th));
      }
      // per-wave drain -> block barrier (all 4 waves drained) -> single publish
      asm volatile("s_waitcnt vmcnt(0)" ::: "memory");
      __syncthreads();
      if (tid == 0)
        __hip_atomic_store(&flg0[s*4 + cw], 1u, __ATOMIC_RELAXED, __HIP_MEMORY_SCOPE_AGENT);
    }
  } else {
    // ---------------- layer-1 role: W1 + R1 in registers ----------------
    const ushort_t* h0 = hbase + (size_t)d*S;          // read (L0 output)
    ushort_t* h1 = hbase + (size_t)(2+d)*S;            // write
    v8s bfr[8][4], bfw[8][4];
    {
      const ushort_t* rpp = rp + (size_t)((d*2+1)*16 + slot)*16384 + l*8;
      const ushort_t* wpp = wp + (size_t)(d*16 + slot)*16384 + l*8;
      #pragma unroll
      for (int f=0;f<32;++f){
        ((v8s*)bfr)[f] = *(const v8s*)(rpp + (size_t)f*512);
        ((v8s*)bfw)[f] = *(const v8s*)(wpp + (size_t)f*512);
      }
    }
    const float* bias = (d ? bias_bw : bias_fw) + 1024;   // layer 1 row
    float bv[4];
    #pragma unroll
    for (int gg=0;gg<4;++gg)
      bv[gg] = bias[gg*256 + U0 + lo] * ((gg==2) ? L2E2 : L2E);
    float c[4] = {0.f,0.f,0.f,0.f};
    for (int s=0;s<256;++s){
      int t = rev ? 255-s : s;
      // wait for h0[t] (flg0[s]) and own h1[t-1] (flg1[s-1]) — paired loads
      {
        unsigned va, vb; int spin = 0;
        const unsigned* fpa = &flg0[s*4 + (l&3)];
        const unsigned* fpb = &flg1[(s>0 ? s-1 : 0)*4 + (l&3)];
        do {
          ld2_flags(fpa, fpb, va, vb);
          if (s == 0) vb = 1u;
          if (++spin > 10000) break;   // failsafe
        } while (!__all((va != 0u) && (vb != 0u)));
        asm volatile("" ::: "memory");
      }
      v4f acc[4];
      #pragma unroll
      for (int gg=0;gg<4;++gg) acc[gg] = (v4f){0.f,0.f,0.f,0.f};
      // a0 = h0[t] fragments (first-touch lines)
      {
        v8s a0[8];
        #pragma unroll
        for (int ks=0;ks<8;++ks)
          a0[ks] = *(const v8s*)(h0 + (size_t)(t*128 + b0 + lo)*UU + ks*32 + hi*8);
        #pragma unroll
        for (int ks=0;ks<8;++ks)
          #pragma unroll
          for (int gg=0;gg<4;++gg)
            acc[gg] = __builtin_amdgcn_mfma_f32_16x16x32_bf16(a0[ks], bfw[ks][gg], acc[gg], 0,0,0);
      }
      if (s>0){
        int tp = rev ? t+1 : t-1;
        v8s a1[8];
        #pragma unroll
        for (int ks=0;ks<8;++ks)
          a1[ks] = *(const v8s*)(h1 + (size_t)(tp*128 + b0 + lo)*UU + ks*32 + hi*8);
        #pragma unroll
        for (int ks=0;ks<8;++ks)
          #pragma unroll
          for (int gg=0;gg<4;++gg)
            acc[gg] = __builtin_amdgcn_mfma_f32_16x16x32_bf16(a1[ks], bfr[ks][gg], acc[gg], 0,0,0);
      }
      #pragma unroll
      for (int r=0;r<4;++r){
        float zi = acc[0][r] + bv[0];
        float zf = acc[1][r] + bv[1];
        float zg = acc[2][r] + bv[2];
        float zo = acc[3][r] + bv[3];
        float ig = __builtin_amdgcn_rcpf(1.f + __builtin_amdgcn_exp2f(-zi));
        float fg = __builtin_amdgcn_rcpf(1.f + __builtin_amdgcn_exp2f(-zf));
        float og = __builtin_amdgcn_rcpf(1.f + __builtin_amdgcn_exp2f(-zo));
        float gt = 1.f - 2.f*__builtin_amdgcn_rcpf(1.f + __builtin_amdgcn_exp2f(zg));
        float cc = fg*c[r] + ig*gt;
        c[r] = cc;
        float th = 1.f - 2.f*__builtin_amdgcn_rcpf(1.f + __builtin_amdgcn_exp2f(L2E2*cc));
        store_short_wt(h1 + (size_t)(t*128 + b0 + hi*4 + r)*UU + U0 + lo, f2bf(og*th));
      }
      asm volatile("s_waitcnt vmcnt(0)" ::: "memory");
      __syncthreads();
      if (tid == 0)
        __hip_atomic_store(&flg1[s*4 + cw], 1u, __ATOMIC_RELAXED, __HIP_MEMORY_SCOPE_AGENT);
    }
  }
}

// ---- final combine: out(B,T,U) fp32 = 0.5*(h1f + h0f + h1b + h0b) ----
__global__ void combine(const ushort_t* __restrict__ h, float* __restrict__ out){
  int tid = blockIdx.x*256 + threadIdx.x;
  int idx = tid*4;
  if (idx >= BB*TT*UU) return;
  int u = idx&255, t = (idx>>8)&255, b = idx>>16;
  size_t o = (size_t)(t*128+b)*256 + u;
  const size_t S = (size_t)TB*UU;
  v4h a0 = *(const v4h*)(h + 0*S + o);   // L0 fw
  v4h a1 = *(const v4h*)(h + 1*S + o);   // L0 bw
  v4h a2 = *(const v4h*)(h + 2*S + o);   // L1 fw
  v4h a3 = *(const v4h*)(h + 3*S + o);   // L1 bw
  v4f res;
  #pragma unroll
  for (int k=0;k<4;++k)
    res[k] = 0.5f*(bf2f(a0[k]) + bf2f(a1[k]) + bf2f(a2[k]) + bf2f(a3[k]));
  *(v4f*)(out + ((size_t)(b*256+t))*256 + u) = res;
}

extern "C" void kernel_launch(void* const* d_in, const int* in_sizes, int n_in,
                              void* d_out, int out_size, void* d_ws, size_t ws_size,
                              hipStream_t stream)
{
  const float* x  = (const float*)d_in[0];
  const float* wf = (const float*)d_in[1];
  const float* rf = (const float*)d_in[2];
  const float* bf = (const float*)d_in[3];
  const float* wb = (const float*)d_in[4];
  const float* rb = (const float*)d_in[5];
  const float* bb = (const float*)d_in[6];
  char* ws = (char*)d_ws;

  // Layout (within the R10-proven budget):
  //   xb [0, 16.7MB) dead after proj L0 -> wp (2MB) + flags (128KB) alias it.
  const size_t XB_OFF = 0;
  const size_t WT_OFF = XB_OFF + (size_t)TB*DD*2;            // 16,777,216
  const size_t RP_OFF = WT_OFF + (size_t)2*1024*256*2;       // +1,048,576
  const size_t XZ_OFF = RP_OFF + (size_t)2*2*256*1024*2;     // +2,097,152
  const size_t H_OFF  = XZ_OFF + (size_t)2*TB*NG*2;          // +134,217,728
  const size_t WP_OFF = XB_OFF;                               // aliases xb
  const size_t FL_OFF = XB_OFF + (size_t)2*256*1024*2;        // aliases xb, after wp
  const size_t FL_BYTES = (size_t)32*1024*4;                  // 131,072

  ushort_t* xb = (ushort_t*)(ws + XB_OFF);
  ushort_t* wt = (ushort_t*)(ws + WT_OFF);
  ushort_t* rp = (ushort_t*)(ws + RP_OFF);
  ushort_t* xz = (ushort_t*)(ws + XZ_OFF);
  ushort_t* h  = (ushort_t*)(ws + H_OFF);
  ushort_t* wp = (ushort_t*)(ws + WP_OFF);
  unsigned* flags = (unsigned*)(ws + FL_OFF);

  prep_x<<<8192,256,0,stream>>>(x, xb);
  prep_w<<<2048,256,0,stream>>>(wf, wb, wt);
  prep_r<<<4096,256,0,stream>>>(rf, rb, rp);
  // layer-0 projection (layer 1 is computed inside the fused recurrence)
  proj_gemm<<<dim3(256,8,2),256,0,stream>>>(xb, wt, bf, bb, xz);
  // xb dead from here: pack W1 fragments + zero flags into its region
  prep_wf<<<2048,256,0,stream>>>(wf, wb, wp);
  hipMemsetAsync(flags, 0, FL_BYTES, stream);
  // fused both-layer recurrence (128 persistent blocks)
  rec_fused<<<128,256,0,stream>>>(xz, rp, wp, bf, bb, h, flags);
  // merge: 0.5*((h1f+h0f)+(h1b+h0b))
  combine<<<8192,256,0,stream>>>(h, (float*)d_out);
}